// Round 10
// baseline (109.798 us; speedup 1.0000x reference)
//
#include <hip/hip_runtime.h>

#define T_TOK 8192
#define D_DIM 128
#define N_NEU 4096
#define RPC 48             // rows per chunk in combo phase
#define NCHUNK 512         // 24576 / RPC

typedef float f4_t __attribute__((ext_vector_type(4)));

// ---------------------------------------------------------------------------
// Kernel A: blocks 0..15  -> acts (last 16 tokens) + window means w=1,2,4,8,16
//                            written DIRECTLY as weighted v rows 0..4.
//           blocks 16..18 -> q/k/v projection (one matrix per block), full
//                            64 KB weight staged to LDS in ONE burst.
// (verified rounds 8-9)
// ---------------------------------------------------------------------------
struct SmemActs {
    float xs16[16][128];   // 8 KB
    float wst[32][256];    // 32 KB staged neuronW chunk
};
struct SmemQkv {
    float xs[32][128];     // 16 KB last-32 tokens
    float w[128][128];     // 64 KB full weight matrix
};
union SmemA {
    SmemActs a;
    SmemQkv q;
};

__global__ void acts_qkv_kernel(
    const float* __restrict__ x,
    const float* __restrict__ neuronW, const float* __restrict__ neuronB,
    const float* __restrict__ Wq, const float* __restrict__ bq,
    const float* __restrict__ Wk, const float* __restrict__ bk,
    const float* __restrict__ Wv, const float* __restrict__ bv,
    const float* __restrict__ ww,    // [6]
    float* __restrict__ v,           // [6][4096] weighted vector (rows 0..4 here)
    float* __restrict__ qkv)         // [3][32][128]
{
    __shared__ SmemA sm;
    const int tid = threadIdx.x;
    const int bid = blockIdx.x;

    if (bid < 16) {
        const int n0 = bid * 256;
        const int n = n0 + tid;
        for (int idx = tid; idx < 16 * 128; idx += 256) {
            int t = idx >> 7, d = idx & 127;
            sm.a.xs16[t][d] = x[(size_t)(T_TOK - 16 + t) * D_DIM + d];
        }
        float acc[16];
        float bias = neuronB[n];
#pragma unroll
        for (int t = 0; t < 16; ++t) acc[t] = bias;
        const f4_t* W4 = reinterpret_cast<const f4_t*>(neuronW);
        f4_t* wst4 = reinterpret_cast<f4_t*>(&sm.a.wst[0][0]);
        for (int c = 0; c < 4; ++c) {
            const int d0 = c * 32;
            __syncthreads();   // wst free (also covers xs16 at c=0)
#pragma unroll
            for (int k = 0; k < 8; ++k) {
                int idx = tid + k * 256;         // 0..2047 float4
                int dd = idx >> 6, j4 = idx & 63;
                wst4[dd * 64 + j4] = W4[(size_t)(d0 + dd) * 1024 + (n0 >> 2) + j4];
            }
            __syncthreads();
#pragma unroll
            for (int dd = 0; dd < 32; ++dd) {
                float w = sm.a.wst[dd][tid];     // conflict-free
#pragma unroll
                for (int t = 0; t < 16; ++t) acc[t] += sm.a.xs16[t][d0 + dd] * w;
            }
        }
#pragma unroll
        for (int t = 0; t < 16; ++t) acc[t] = tanhf(acc[t]);  // |tanh|<=1 => clip no-op
        float denom = 0.1f;
#pragma unroll
        for (int i = 0; i < 6; ++i) denom += ww[i];
        const float inv = 1.f / denom;
        float s1 = acc[15];
        float s2 = s1 + acc[14];
        float s4 = s2 + acc[13] + acc[12];
        float s8 = s4 + acc[11] + acc[10] + acc[9] + acc[8];
        float s16 = s8 + acc[7] + acc[6] + acc[5] + acc[4] + acc[3] + acc[2] + acc[1] + acc[0];
        v[0 * N_NEU + n] = s1 * ((ww[0] + 0.1f) * inv);
        v[1 * N_NEU + n] = s2 * 0.5f * ((ww[1] + 0.1f) * inv);
        v[2 * N_NEU + n] = s4 * 0.25f * ((ww[2] + 0.1f) * inv);
        v[3 * N_NEU + n] = s8 * 0.125f * ((ww[3] + 0.1f) * inv);
        v[4 * N_NEU + n] = s16 * 0.0625f * ((ww[4] + 0.1f) * inv);
        return;
    }

    // ---- blocks 16..18: one q/k/v matrix each, full-W single-burst staging --
    const int m = bid - 16;
    const float* Wm = (m == 0) ? Wq : ((m == 1) ? Wk : Wv);
    const float* bb = (m == 0) ? bq : ((m == 1) ? bk : bv);

    f4_t* xs4 = reinterpret_cast<f4_t*>(&sm.q.xs[0][0]);
    const f4_t* X4 = reinterpret_cast<const f4_t*>(x + (size_t)(T_TOK - 32) * D_DIM);
#pragma unroll
    for (int k = 0; k < 4; ++k) xs4[tid + k * 256] = X4[tid + k * 256];
    f4_t* w4 = reinterpret_cast<f4_t*>(&sm.q.w[0][0]);
    const f4_t* Wm4 = reinterpret_cast<const f4_t*>(Wm);
#pragma unroll
    for (int k = 0; k < 16; ++k) w4[tid + k * 256] = Wm4[tid + k * 256];
    __syncthreads();

    const int d = tid & 127;
    const int g = tid >> 7;
    float acc[16];
    float bias = bb[d];
#pragma unroll
    for (int i = 0; i < 16; ++i) acc[i] = bias;
#pragma unroll 4
    for (int e = 0; e < 128; ++e) {
        float w = sm.q.w[e][d];
#pragma unroll
        for (int i = 0; i < 16; ++i) acc[i] += sm.q.xs[g * 16 + i][e] * w;
    }
#pragma unroll
    for (int i = 0; i < 16; ++i) qkv[m * 4096 + (g * 16 + i) * 128 + d] = acc[i];
}

// ---------------------------------------------------------------------------
// Kernel B: attn chain + proj, fused. 16 blocks x 256; every block
// redundantly recomputes the tiny attention chain, then projects its own
// 256 columns with staged projW and writes weighted v row 5.
// (verified round 9)
// ---------------------------------------------------------------------------
struct SmemAP {
    union {
        struct {
            float qs[32][128];
            float kt[128][33];
            float vs[32][128];
            float ps[32][33];
            float pbar[32];
            float mvec[128];
            float red[2];
        } a;
        struct {
            float wst[32][256];
        } p;
    } u;
    float ys[128];   // LayerNorm output, survives the union switch
};

__global__ void attn_proj_kernel(
    const float* __restrict__ qkv,
    const float* __restrict__ ln_g, const float* __restrict__ ln_b,
    const float* __restrict__ projW,   // [128][4096]
    const float* __restrict__ projb,
    const float* __restrict__ ww,
    float* __restrict__ v)             // writes [5*4096 .. 6*4096)
{
    __shared__ SmemAP sm;
    const int tid = threadIdx.x;

    for (int idx = tid; idx < 32 * 128; idx += 256) {
        int i = idx >> 7, d = idx & 127;
        sm.u.a.qs[i][d] = qkv[idx];
        sm.u.a.kt[d][i] = qkv[4096 + idx];
        sm.u.a.vs[i][d] = qkv[8192 + idx];
    }
    __syncthreads();
    const float scale = 0.08838834764831845f;  // 1/sqrt(128)
#pragma unroll
    for (int rep = 0; rep < 4; ++rep) {
        int idx = tid + rep * 256;
        int i = idx >> 5, j = idx & 31;
        float acc = 0.f;
        for (int e = 0; e < 128; ++e) acc += sm.u.a.qs[i][e] * sm.u.a.kt[e][j];
        sm.u.a.ps[i][j] = acc * scale;
    }
    __syncthreads();
    if (tid < 32) {
        float mx = -1e30f;
        for (int j = 0; j < 32; ++j) mx = fmaxf(mx, sm.u.a.ps[tid][j]);
        float s = 0.f;
        for (int j = 0; j < 32; ++j) { float e = expf(sm.u.a.ps[tid][j] - mx); sm.u.a.ps[tid][j] = e; s += e; }
        float inv = 1.f / s;
        for (int j = 0; j < 32; ++j) sm.u.a.ps[tid][j] *= inv;
    }
    __syncthreads();
    if (tid < 32) {
        float s = 0.f;
        for (int i = 0; i < 32; ++i) s += sm.u.a.ps[i][tid];
        sm.u.a.pbar[tid] = s * (1.f / 32.f);
    }
    __syncthreads();
    if (tid < 128) {
        float s = 0.f;
        for (int j = 0; j < 32; ++j) s += sm.u.a.pbar[j] * sm.u.a.vs[j][tid];
        sm.u.a.mvec[tid] = s;
    }
    __syncthreads();
    if (tid < 64) {
        float p = sm.u.a.mvec[tid] + sm.u.a.mvec[tid + 64];
        for (int off = 32; off; off >>= 1) p += __shfl_down(p, off);
        if (tid == 0) sm.u.a.red[0] = p * (1.f / 128.f);
    }
    __syncthreads();
    float mu = sm.u.a.red[0];
    if (tid < 64) {
        float t1 = sm.u.a.mvec[tid] - mu, t2 = sm.u.a.mvec[tid + 64] - mu;
        float p = t1 * t1 + t2 * t2;
        for (int off = 32; off; off >>= 1) p += __shfl_down(p, off);
        if (tid == 0) sm.u.a.red[1] = rsqrtf(p * (1.f / 128.f) + 1e-5f);
    }
    __syncthreads();
    if (tid < 128) {
        sm.ys[tid] = (sm.u.a.mvec[tid] - mu) * sm.u.a.red[1] * ln_g[tid] + ln_b[tid];
    }
    __syncthreads();   // attn LDS dead; ys live

    const int n0 = blockIdx.x * 256;
    const int n = n0 + tid;
    float denom = 0.1f;
#pragma unroll
    for (int i = 0; i < 6; ++i) denom += ww[i];
    const float nw5 = (ww[5] + 0.1f) / denom;

    float acc = projb[n];
    const f4_t* P4 = reinterpret_cast<const f4_t*>(projW);
    f4_t* wst4 = reinterpret_cast<f4_t*>(&sm.u.p.wst[0][0]);
    for (int c = 0; c < 4; ++c) {
        const int d0 = c * 32;
        __syncthreads();
#pragma unroll
        for (int k = 0; k < 8; ++k) {
            int idx = tid + k * 256;
            int dd = idx >> 6, j4 = idx & 63;
            wst4[dd * 64 + j4] = P4[(size_t)(d0 + dd) * 1024 + (n0 >> 2) + j4];
        }
        __syncthreads();
#pragma unroll
        for (int dd = 0; dd < 32; ++dd) {
            acc += sm.ys[d0 + dd] * sm.u.p.wst[dd][tid];
        }
    }
    v[5 * N_NEU + n] = acc * nw5;
}

// ---------------------------------------------------------------------------
// Kernel C: combo partials — FULLY CONTIGUOUS per-block stream.
// 512 blocks x 256 threads (2/CU). Block = 48 rows x FULL 4096-col width:
// 4 f4 accumulators/thread, 4 x 16 B nt-loads per row cover the whole 16 KB
// row; rows sequential -> 768 KB of strictly sequential addresses per block.
// part stored with PLAIN stores (8 MB, stays cache-hot for the reduce).
// ---------------------------------------------------------------------------
__global__ __launch_bounds__(256) void combo_partial_kernel(
    const float* __restrict__ v,       // [24576]
    const float* __restrict__ comboW,  // [24576][4096]
    float* __restrict__ part)          // [NCHUNK][4096]
{
    __shared__ float vsm[RPC];
    const int tid = threadIdx.x;
    const int chunk = blockIdx.x;
    const int row0 = chunk * RPC;

    if (tid < RPC) vsm[tid] = v[row0 + tid];
    __syncthreads();

    const f4_t* W4 = reinterpret_cast<const f4_t*>(comboW);
    const size_t base = (size_t)row0 * 1024 + tid;   // float4 index
    f4_t acc0 = {0.f,0.f,0.f,0.f}, acc1 = {0.f,0.f,0.f,0.f};
    f4_t acc2 = {0.f,0.f,0.f,0.f}, acc3 = {0.f,0.f,0.f,0.f};
#pragma unroll 4
    for (int r = 0; r < RPC; ++r) {
        const float vr = vsm[r];                      // LDS broadcast
        const size_t b = base + (size_t)r * 1024;
        f4_t w0 = __builtin_nontemporal_load(&W4[b]);
        f4_t w1 = __builtin_nontemporal_load(&W4[b + 256]);
        f4_t w2 = __builtin_nontemporal_load(&W4[b + 512]);
        f4_t w3 = __builtin_nontemporal_load(&W4[b + 768]);
        acc0 += w0 * vr; acc1 += w1 * vr; acc2 += w2 * vr; acc3 += w3 * vr;
    }
    f4_t* P = reinterpret_cast<f4_t*>(part) + (size_t)chunk * 1024 + tid;
    P[0]   = acc0;
    P[256] = acc1;
    P[512] = acc2;
    P[768] = acc3;
}

// ---------------------------------------------------------------------------
// Kernel D: reduce 512 partials + bias. 32 blocks x 256, f4 cols,
// 8-way chunk split (64-deep chains) + LDS combine.
// ---------------------------------------------------------------------------
__global__ void combo_reduce_kernel(const float* __restrict__ part,
                                    const float* __restrict__ bias,
                                    float* __restrict__ out)
{
    __shared__ f4_t red[8][32];
    const int tid = threadIdx.x;
    const int h = tid >> 5;                 // 0..7: chunk eighth (64 each)
    const int j = tid & 31;
    const int n4 = blockIdx.x * 32 + j;     // 32 blocks x 32 f4 = 1024 f4
    const f4_t* P4 = reinterpret_cast<const f4_t*>(part);
    f4_t acc = {0.f,0.f,0.f,0.f};
#pragma unroll 8
    for (int c = h * 64; c < h * 64 + 64; ++c)
        acc += P4[(size_t)c * 1024 + n4];
    red[h][j] = acc;
    __syncthreads();
    if (h == 0) {
        f4_t s = red[0][j] + red[1][j] + red[2][j] + red[3][j]
               + red[4][j] + red[5][j] + red[6][j] + red[7][j];
        s += reinterpret_cast<const f4_t*>(bias)[n4];
        reinterpret_cast<f4_t*>(out)[n4] = s;
    }
}

// ---------------------------------------------------------------------------
extern "C" void kernel_launch(void* const* d_in, const int* in_sizes, int n_in,
                              void* d_out, int out_size, void* d_ws, size_t ws_size,
                              hipStream_t stream) {
    const float* inputEmbeds = (const float*)d_in[0];
    const float* neuronW     = (const float*)d_in[1];
    const float* neuronB     = (const float*)d_in[2];
    const float* Wq          = (const float*)d_in[3];
    const float* bq          = (const float*)d_in[4];
    const float* Wk          = (const float*)d_in[5];
    const float* bk          = (const float*)d_in[6];
    const float* Wv          = (const float*)d_in[7];
    const float* bv          = (const float*)d_in[8];
    const float* ln_g        = (const float*)d_in[9];
    const float* ln_b        = (const float*)d_in[10];
    const float* projW       = (const float*)d_in[11];
    const float* projb       = (const float*)d_in[12];
    const float* ww          = (const float*)d_in[13];
    const float* comboW      = (const float*)d_in[14];
    const float* combob      = (const float*)d_in[15];
    float* out = (float*)d_out;
    float* ws  = (float*)d_ws;

    float* v    = ws;                 // 6*4096 = 24576
    float* qkv  = ws + 24576;         // 3*4096 = 12288
    float* part = ws + 36864;         // NCHUNK*4096 = 2097152 (8 MB)

    acts_qkv_kernel<<<19, 256, 0, stream>>>(inputEmbeds, neuronW, neuronB,
                                            Wq, bq, Wk, bk, Wv, bv, ww, v, qkv);
    attn_proj_kernel<<<16, 256, 0, stream>>>(qkv, ln_g, ln_b, projW, projb, ww, v);
    combo_partial_kernel<<<NCHUNK, 256, 0, stream>>>(v, comboW, part);
    combo_reduce_kernel<<<32, 256, 0, stream>>>(part, combob, out);
}

// Round 11
// 107.438 us; speedup vs baseline: 1.0220x; 1.0220x over previous
//
#include <hip/hip_runtime.h>

#define T_TOK 8192
#define D_DIM 128
#define N_NEU 4096
#define RPC 48             // rows per chunk in combo phase
#define NCHUNK 512         // 24576 / RPC
#define PLAIN_CHUNKS 256   // chunks 0..255 (192 MB) use plain loads -> LLC-resident

typedef float f4_t __attribute__((ext_vector_type(4)));

// ---------------------------------------------------------------------------
// Kernel A: blocks 0..15  -> acts (last 16 tokens) + window means w=1,2,4,8,16
//                            written DIRECTLY as weighted v rows 0..4.
//           blocks 16..18 -> q/k/v projection (one matrix per block), full
//                            64 KB weight staged to LDS in ONE burst.
// (verified rounds 8-10)
// ---------------------------------------------------------------------------
struct SmemActs {
    float xs16[16][128];   // 8 KB
    float wst[32][256];    // 32 KB staged neuronW chunk
};
struct SmemQkv {
    float xs[32][128];     // 16 KB last-32 tokens
    float w[128][128];     // 64 KB full weight matrix
};
union SmemA {
    SmemActs a;
    SmemQkv q;
};

__global__ void acts_qkv_kernel(
    const float* __restrict__ x,
    const float* __restrict__ neuronW, const float* __restrict__ neuronB,
    const float* __restrict__ Wq, const float* __restrict__ bq,
    const float* __restrict__ Wk, const float* __restrict__ bk,
    const float* __restrict__ Wv, const float* __restrict__ bv,
    const float* __restrict__ ww,    // [6]
    float* __restrict__ v,           // [6][4096] weighted vector (rows 0..4 here)
    float* __restrict__ qkv)         // [3][32][128]
{
    __shared__ SmemA sm;
    const int tid = threadIdx.x;
    const int bid = blockIdx.x;

    if (bid < 16) {
        const int n0 = bid * 256;
        const int n = n0 + tid;
        for (int idx = tid; idx < 16 * 128; idx += 256) {
            int t = idx >> 7, d = idx & 127;
            sm.a.xs16[t][d] = x[(size_t)(T_TOK - 16 + t) * D_DIM + d];
        }
        float acc[16];
        float bias = neuronB[n];
#pragma unroll
        for (int t = 0; t < 16; ++t) acc[t] = bias;
        const f4_t* W4 = reinterpret_cast<const f4_t*>(neuronW);
        f4_t* wst4 = reinterpret_cast<f4_t*>(&sm.a.wst[0][0]);
        for (int c = 0; c < 4; ++c) {
            const int d0 = c * 32;
            __syncthreads();   // wst free (also covers xs16 at c=0)
#pragma unroll
            for (int k = 0; k < 8; ++k) {
                int idx = tid + k * 256;         // 0..2047 float4
                int dd = idx >> 6, j4 = idx & 63;
                wst4[dd * 64 + j4] = W4[(size_t)(d0 + dd) * 1024 + (n0 >> 2) + j4];
            }
            __syncthreads();
#pragma unroll
            for (int dd = 0; dd < 32; ++dd) {
                float w = sm.a.wst[dd][tid];     // conflict-free
#pragma unroll
                for (int t = 0; t < 16; ++t) acc[t] += sm.a.xs16[t][d0 + dd] * w;
            }
        }
#pragma unroll
        for (int t = 0; t < 16; ++t) acc[t] = tanhf(acc[t]);  // |tanh|<=1 => clip no-op
        float denom = 0.1f;
#pragma unroll
        for (int i = 0; i < 6; ++i) denom += ww[i];
        const float inv = 1.f / denom;
        float s1 = acc[15];
        float s2 = s1 + acc[14];
        float s4 = s2 + acc[13] + acc[12];
        float s8 = s4 + acc[11] + acc[10] + acc[9] + acc[8];
        float s16 = s8 + acc[7] + acc[6] + acc[5] + acc[4] + acc[3] + acc[2] + acc[1] + acc[0];
        v[0 * N_NEU + n] = s1 * ((ww[0] + 0.1f) * inv);
        v[1 * N_NEU + n] = s2 * 0.5f * ((ww[1] + 0.1f) * inv);
        v[2 * N_NEU + n] = s4 * 0.25f * ((ww[2] + 0.1f) * inv);
        v[3 * N_NEU + n] = s8 * 0.125f * ((ww[3] + 0.1f) * inv);
        v[4 * N_NEU + n] = s16 * 0.0625f * ((ww[4] + 0.1f) * inv);
        return;
    }

    // ---- blocks 16..18: one q/k/v matrix each, full-W single-burst staging --
    const int m = bid - 16;
    const float* Wm = (m == 0) ? Wq : ((m == 1) ? Wk : Wv);
    const float* bb = (m == 0) ? bq : ((m == 1) ? bk : bv);

    f4_t* xs4 = reinterpret_cast<f4_t*>(&sm.q.xs[0][0]);
    const f4_t* X4 = reinterpret_cast<const f4_t*>(x + (size_t)(T_TOK - 32) * D_DIM);
#pragma unroll
    for (int k = 0; k < 4; ++k) xs4[tid + k * 256] = X4[tid + k * 256];
    f4_t* w4 = reinterpret_cast<f4_t*>(&sm.q.w[0][0]);
    const f4_t* Wm4 = reinterpret_cast<const f4_t*>(Wm);
#pragma unroll
    for (int k = 0; k < 16; ++k) w4[tid + k * 256] = Wm4[tid + k * 256];
    __syncthreads();

    const int d = tid & 127;
    const int g = tid >> 7;
    float acc[16];
    float bias = bb[d];
#pragma unroll
    for (int i = 0; i < 16; ++i) acc[i] = bias;
#pragma unroll 4
    for (int e = 0; e < 128; ++e) {
        float w = sm.q.w[e][d];
#pragma unroll
        for (int i = 0; i < 16; ++i) acc[i] += sm.q.xs[g * 16 + i][e] * w;
    }
#pragma unroll
    for (int i = 0; i < 16; ++i) qkv[m * 4096 + (g * 16 + i) * 128 + d] = acc[i];
}

// ---------------------------------------------------------------------------
// Kernel B: attn chain + proj, fused. 16 blocks x 256; every block
// redundantly recomputes the tiny attention chain, then projects its own
// 256 columns with staged projW and writes weighted v row 5.
// (verified rounds 9-10)
// ---------------------------------------------------------------------------
struct SmemAP {
    union {
        struct {
            float qs[32][128];
            float kt[128][33];
            float vs[32][128];
            float ps[32][33];
            float pbar[32];
            float mvec[128];
            float red[2];
        } a;
        struct {
            float wst[32][256];
        } p;
    } u;
    float ys[128];   // LayerNorm output, survives the union switch
};

__global__ void attn_proj_kernel(
    const float* __restrict__ qkv,
    const float* __restrict__ ln_g, const float* __restrict__ ln_b,
    const float* __restrict__ projW,   // [128][4096]
    const float* __restrict__ projb,
    const float* __restrict__ ww,
    float* __restrict__ v)             // writes [5*4096 .. 6*4096)
{
    __shared__ SmemAP sm;
    const int tid = threadIdx.x;

    for (int idx = tid; idx < 32 * 128; idx += 256) {
        int i = idx >> 7, d = idx & 127;
        sm.u.a.qs[i][d] = qkv[idx];
        sm.u.a.kt[d][i] = qkv[4096 + idx];
        sm.u.a.vs[i][d] = qkv[8192 + idx];
    }
    __syncthreads();
    const float scale = 0.08838834764831845f;  // 1/sqrt(128)
#pragma unroll
    for (int rep = 0; rep < 4; ++rep) {
        int idx = tid + rep * 256;
        int i = idx >> 5, j = idx & 31;
        float acc = 0.f;
        for (int e = 0; e < 128; ++e) acc += sm.u.a.qs[i][e] * sm.u.a.kt[e][j];
        sm.u.a.ps[i][j] = acc * scale;
    }
    __syncthreads();
    if (tid < 32) {
        float mx = -1e30f;
        for (int j = 0; j < 32; ++j) mx = fmaxf(mx, sm.u.a.ps[tid][j]);
        float s = 0.f;
        for (int j = 0; j < 32; ++j) { float e = expf(sm.u.a.ps[tid][j] - mx); sm.u.a.ps[tid][j] = e; s += e; }
        float inv = 1.f / s;
        for (int j = 0; j < 32; ++j) sm.u.a.ps[tid][j] *= inv;
    }
    __syncthreads();
    if (tid < 32) {
        float s = 0.f;
        for (int i = 0; i < 32; ++i) s += sm.u.a.ps[i][tid];
        sm.u.a.pbar[tid] = s * (1.f / 32.f);
    }
    __syncthreads();
    if (tid < 128) {
        float s = 0.f;
        for (int j = 0; j < 32; ++j) s += sm.u.a.pbar[j] * sm.u.a.vs[j][tid];
        sm.u.a.mvec[tid] = s;
    }
    __syncthreads();
    if (tid < 64) {
        float p = sm.u.a.mvec[tid] + sm.u.a.mvec[tid + 64];
        for (int off = 32; off; off >>= 1) p += __shfl_down(p, off);
        if (tid == 0) sm.u.a.red[0] = p * (1.f / 128.f);
    }
    __syncthreads();
    float mu = sm.u.a.red[0];
    if (tid < 64) {
        float t1 = sm.u.a.mvec[tid] - mu, t2 = sm.u.a.mvec[tid + 64] - mu;
        float p = t1 * t1 + t2 * t2;
        for (int off = 32; off; off >>= 1) p += __shfl_down(p, off);
        if (tid == 0) sm.u.a.red[1] = rsqrtf(p * (1.f / 128.f) + 1e-5f);
    }
    __syncthreads();
    if (tid < 128) {
        sm.ys[tid] = (sm.u.a.mvec[tid] - mu) * sm.u.a.red[1] * ln_g[tid] + ln_b[tid];
    }
    __syncthreads();   // attn LDS dead; ys live

    const int n0 = blockIdx.x * 256;
    const int n = n0 + tid;
    float denom = 0.1f;
#pragma unroll
    for (int i = 0; i < 6; ++i) denom += ww[i];
    const float nw5 = (ww[5] + 0.1f) / denom;

    float acc = projb[n];
    const f4_t* P4 = reinterpret_cast<const f4_t*>(projW);
    f4_t* wst4 = reinterpret_cast<f4_t*>(&sm.u.p.wst[0][0]);
    for (int c = 0; c < 4; ++c) {
        const int d0 = c * 32;
        __syncthreads();
#pragma unroll
        for (int k = 0; k < 8; ++k) {
            int idx = tid + k * 256;
            int dd = idx >> 6, j4 = idx & 63;
            wst4[dd * 64 + j4] = P4[(size_t)(d0 + dd) * 1024 + (n0 >> 2) + j4];
        }
        __syncthreads();
#pragma unroll
        for (int dd = 0; dd < 32; ++dd) {
            acc += sm.ys[d0 + dd] * sm.u.p.wst[dd][tid];
        }
    }
    v[5 * N_NEU + n] = acc * nw5;
}

// ---------------------------------------------------------------------------
// Kernel C: combo partials — HYBRID cache split.
// chunks 0..PLAIN_CHUNKS-1 (rows 0..12287, 192 MB): PLAIN loads. This region
//   fits the 256 MB LLC with slack and nothing else big allocates (nt region
//   bypasses, part is 8 MB) -> ~fully L3-resident across replays.
// chunks PLAIN_CHUNKS..511 (224 MB): NONTEMPORAL loads -> clean HBM stream,
//   no LLC pollution.
// 512 blocks x 256 threads (2/CU: one plain + one nt block per CU).
// Block = 48 rows x full 4096-col width (contiguous 768 KB).
// ---------------------------------------------------------------------------
__global__ __launch_bounds__(256) void combo_partial_kernel(
    const float* __restrict__ v,       // [24576]
    const float* __restrict__ comboW,  // [24576][4096]
    float* __restrict__ part)          // [NCHUNK][4096]
{
    __shared__ float vsm[RPC];
    const int tid = threadIdx.x;
    const int chunk = blockIdx.x;
    const int row0 = chunk * RPC;

    if (tid < RPC) vsm[tid] = v[row0 + tid];
    __syncthreads();

    const f4_t* W4 = reinterpret_cast<const f4_t*>(comboW);
    const size_t base = (size_t)row0 * 1024 + tid;   // float4 index
    f4_t acc0 = {0.f,0.f,0.f,0.f}, acc1 = {0.f,0.f,0.f,0.f};
    f4_t acc2 = {0.f,0.f,0.f,0.f}, acc3 = {0.f,0.f,0.f,0.f};

    if (chunk < PLAIN_CHUNKS) {
#pragma unroll 4
        for (int r = 0; r < RPC; ++r) {
            const float vr = vsm[r];                  // LDS broadcast
            const size_t b = base + (size_t)r * 1024;
            f4_t w0 = W4[b];
            f4_t w1 = W4[b + 256];
            f4_t w2 = W4[b + 512];
            f4_t w3 = W4[b + 768];
            acc0 += w0 * vr; acc1 += w1 * vr; acc2 += w2 * vr; acc3 += w3 * vr;
        }
    } else {
#pragma unroll 4
        for (int r = 0; r < RPC; ++r) {
            const float vr = vsm[r];
            const size_t b = base + (size_t)r * 1024;
            f4_t w0 = __builtin_nontemporal_load(&W4[b]);
            f4_t w1 = __builtin_nontemporal_load(&W4[b + 256]);
            f4_t w2 = __builtin_nontemporal_load(&W4[b + 512]);
            f4_t w3 = __builtin_nontemporal_load(&W4[b + 768]);
            acc0 += w0 * vr; acc1 += w1 * vr; acc2 += w2 * vr; acc3 += w3 * vr;
        }
    }
    f4_t* P = reinterpret_cast<f4_t*>(part) + (size_t)chunk * 1024 + tid;
    P[0]   = acc0;
    P[256] = acc1;
    P[512] = acc2;
    P[768] = acc3;
}

// ---------------------------------------------------------------------------
// Kernel D: reduce 512 partials + bias. 32 blocks x 256, f4 cols,
// 8-way chunk split (64-deep chains) + LDS combine.
// ---------------------------------------------------------------------------
__global__ void combo_reduce_kernel(const float* __restrict__ part,
                                    const float* __restrict__ bias,
                                    float* __restrict__ out)
{
    __shared__ f4_t red[8][32];
    const int tid = threadIdx.x;
    const int h = tid >> 5;                 // 0..7: chunk eighth (64 each)
    const int j = tid & 31;
    const int n4 = blockIdx.x * 32 + j;     // 32 blocks x 32 f4 = 1024 f4
    const f4_t* P4 = reinterpret_cast<const f4_t*>(part);
    f4_t acc = {0.f,0.f,0.f,0.f};
#pragma unroll 8
    for (int c = h * 64; c < h * 64 + 64; ++c)
        acc += P4[(size_t)c * 1024 + n4];
    red[h][j] = acc;
    __syncthreads();
    if (h == 0) {
        f4_t s = red[0][j] + red[1][j] + red[2][j] + red[3][j]
               + red[4][j] + red[5][j] + red[6][j] + red[7][j];
        s += reinterpret_cast<const f4_t*>(bias)[n4];
        reinterpret_cast<f4_t*>(out)[n4] = s;
    }
}

// ---------------------------------------------------------------------------
extern "C" void kernel_launch(void* const* d_in, const int* in_sizes, int n_in,
                              void* d_out, int out_size, void* d_ws, size_t ws_size,
                              hipStream_t stream) {
    const float* inputEmbeds = (const float*)d_in[0];
    const float* neuronW     = (const float*)d_in[1];
    const float* neuronB     = (const float*)d_in[2];
    const float* Wq          = (const float*)d_in[3];
    const float* bq          = (const float*)d_in[4];
    const float* Wk          = (const float*)d_in[5];
    const float* bk          = (const float*)d_in[6];
    const float* Wv          = (const float*)d_in[7];
    const float* bv          = (const float*)d_in[8];
    const float* ln_g        = (const float*)d_in[9];
    const float* ln_b        = (const float*)d_in[10];
    const float* projW       = (const float*)d_in[11];
    const float* projb       = (const float*)d_in[12];
    const float* ww          = (const float*)d_in[13];
    const float* comboW      = (const float*)d_in[14];
    const float* combob      = (const float*)d_in[15];
    float* out = (float*)d_out;
    float* ws  = (float*)d_ws;

    float* v    = ws;                 // 6*4096 = 24576
    float* qkv  = ws + 24576;         // 3*4096 = 12288
    float* part = ws + 36864;         // NCHUNK*4096 = 2097152 (8 MB)

    acts_qkv_kernel<<<19, 256, 0, stream>>>(inputEmbeds, neuronW, neuronB,
                                            Wq, bq, Wk, bk, Wv, bv, ww, v, qkv);
    attn_proj_kernel<<<16, 256, 0, stream>>>(qkv, ln_g, ln_b, projW, projb, ww, v);
    combo_partial_kernel<<<NCHUNK, 256, 0, stream>>>(v, comboW, part);
    combo_reduce_kernel<<<32, 256, 0, stream>>>(part, combob, out);
}